// Round 1
// baseline (975.512 us; speedup 1.0000x reference)
//
#include <hip/hip_runtime.h>
#include <math.h>

// Problem constants (match reference)
namespace {
constexpr int Bn    = 2048;
constexpr int CELLn = 512;
constexpr int Kn    = 30;   // alpha/beta/kappa each [B,30]
constexpr int Ln    = 1024; // padded text len
constexpr int Vn    = 80;   // vocab
constexpr int NT    = 320;  // 5 waves; 320 = 16 row-groups x 20 col-quads for the w phase
}

__global__ __launch_bounds__(NT) void window_kernel(
    const float* __restrict__ x,          // [B, CELL]
    const float* __restrict__ kappa_old,  // [B, K]
    const float* __restrict__ onehots,    // [B, L, V]
    const float* __restrict__ text_lens,  // [B, 1]
    const float* __restrict__ W,          // [3K, CELL]
    const float* __restrict__ bias,       // [3K]
    float* __restrict__ out_w,            // [B, V]
    float* __restrict__ out_kappa,        // [B, K]
    float* __restrict__ out_phi)          // [B, L+1]
{
    const int b = blockIdx.x;
    const int t = threadIdx.x;

    __shared__ float s_x[CELLn];          // 2 KB
    __shared__ float s_abk[3 * Kn];       // alpha[0:30], beta[30:60], kappa[60:90]
    __shared__ float s_phi[Ln];           // 4 KB, scaled phi for l < 1024
    __shared__ float s_red[16][Vn];       // 5 KB, w partial sums

    // ---- stage x row ----
    for (int i = t; i < CELLn; i += NT) s_x[i] = x[(size_t)b * CELLn + i];
    __syncthreads();

    // ---- phase 1: params = exp(x @ W.T + b); kappa = kappa_old + pre_kappa ----
    if (t < 3 * Kn) {
        const float4* wrow = (const float4*)(W + (size_t)t * CELLn);
        const float4* xr   = (const float4*)s_x;
        float a0 = 0.f, a1 = 0.f, a2 = 0.f, a3 = 0.f;
        #pragma unroll 8
        for (int i = 0; i < CELLn / 4; ++i) {
            float4 wv = wrow[i];
            float4 xv = xr[i];
            a0 = fmaf(wv.x, xv.x, a0);
            a1 = fmaf(wv.y, xv.y, a1);
            a2 = fmaf(wv.z, xv.z, a2);
            a3 = fmaf(wv.w, xv.w, a3);
        }
        float val = expf((a0 + a1) + (a2 + a3) + bias[t]);
        if (t >= 2 * Kn) {  // pre_kappa -> kappa
            int k = t - 2 * Kn;
            float kap = kappa_old[(size_t)b * Kn + k] + val;
            s_abk[t] = kap;
            out_kappa[(size_t)b * Kn + k] = kap;
        } else {
            s_abk[t] = val;  // alpha or beta
        }
    }
    __syncthreads();

    // ---- phase 2: phi[l] = scale * sum_k alpha_k * exp(-beta_k*(kappa_k-l)^2) ----
    const float scale = (float)Ln / text_lens[b];
    for (int l = t; l <= Ln; l += NT) {
        const float fl = (float)l;
        float acc = 0.f;
        #pragma unroll
        for (int k = 0; k < Kn; ++k) {
            float d = s_abk[2 * Kn + k] - fl;
            acc = fmaf(s_abk[k], expf(-s_abk[Kn + k] * d * d), acc);
        }
        float ph = acc * scale;
        out_phi[(size_t)b * (Ln + 1) + l] = ph;
        if (l < Ln) s_phi[l] = ph;
    }
    __syncthreads();

    // ---- phase 3: w[v] = sum_l phi[l] * onehots[b,l,v] (671 MB stream, the bottleneck) ----
    const int j  = t % 20;   // column quad: v = 4j..4j+3
    const int r0 = t / 20;   // row phase 0..15
    const float4* oh = (const float4*)(onehots + (size_t)b * Ln * Vn);
    float4 acc4 = make_float4(0.f, 0.f, 0.f, 0.f);
    for (int l = r0; l < Ln; l += 16) {
        float4 v = oh[l * 20 + j];   // wave = 64 consecutive float4s -> 1 KB coalesced
        float ph = s_phi[l];
        acc4.x = fmaf(ph, v.x, acc4.x);
        acc4.y = fmaf(ph, v.y, acc4.y);
        acc4.z = fmaf(ph, v.z, acc4.z);
        acc4.w = fmaf(ph, v.w, acc4.w);
    }
    *((float4*)&s_red[r0][j * 4]) = acc4;
    __syncthreads();

    if (t < Vn) {
        float s = 0.f;
        #pragma unroll
        for (int r = 0; r < 16; ++r) s += s_red[r][t];
        out_w[(size_t)b * Vn + t] = s;
    }
}

extern "C" void kernel_launch(void* const* d_in, const int* in_sizes, int n_in,
                              void* d_out, int out_size, void* d_ws, size_t ws_size,
                              hipStream_t stream) {
    const float* x         = (const float*)d_in[0];
    const float* kappa_old = (const float*)d_in[1];
    const float* onehots   = (const float*)d_in[2];
    const float* text_lens = (const float*)d_in[3];
    const float* W         = (const float*)d_in[4];
    const float* bias      = (const float*)d_in[5];

    float* out       = (float*)d_out;
    float* out_w     = out;                                  // [B, V]
    float* out_kappa = out + (size_t)Bn * Vn;                // [B, K]
    float* out_phi   = out_kappa + (size_t)Bn * Kn;          // [B, L+1]

    window_kernel<<<Bn, NT, 0, stream>>>(x, kappa_old, onehots, text_lens, W, bias,
                                         out_w, out_kappa, out_phi);
}

// Round 2
// 921.861 us; speedup vs baseline: 1.0582x; 1.0582x over previous
//
#include <hip/hip_runtime.h>
#include <math.h>

// Problem constants (match reference)
namespace {
constexpr int Bn    = 2048;
constexpr int CELLn = 512;
constexpr int Kn    = 30;   // alpha/beta/kappa each [B,30]
constexpr int Ln    = 1024; // padded text len
constexpr int Vn    = 80;   // vocab
constexpr int NTA   = 256;  // kernel A block
constexpr int NTB   = 320;  // kernel B block: 16 row-phases x 20 col-quads
constexpr int CH    = 4;    // l-chunks per batch row in kernel B
constexpr int CHL   = Ln / CH;  // 256 rows per chunk
}

// Kernel A: params = exp(x@W.T + b), kappa = kappa_old + pre_kappa, phi.
// Also zeroes out_w for kernel B's atomic accumulation.
__global__ __launch_bounds__(NTA) void window_params_phi(
    const float* __restrict__ x,          // [B, CELL]
    const float* __restrict__ kappa_old,  // [B, K]
    const float* __restrict__ text_lens,  // [B, 1]
    const float* __restrict__ W,          // [3K, CELL]
    const float* __restrict__ bias,       // [3K]
    float* __restrict__ out_w,            // [B, V]  (zeroed here)
    float* __restrict__ out_kappa,        // [B, K]
    float* __restrict__ out_phi)          // [B, L+1]
{
    const int b = blockIdx.x;
    const int t = threadIdx.x;

    __shared__ float s_x[CELLn];    // 2 KB
    __shared__ float s_abk[3 * Kn]; // alpha[0:30], beta[30:60], kappa[60:90]

    // stage x row (threads 0..127) while threads 128..207 zero out_w
    if (t < 128) ((float4*)s_x)[t] = ((const float4*)(x + (size_t)b * CELLn))[t];
    if (t >= 128 && t < 128 + Vn) out_w[(size_t)b * Vn + (t - 128)] = 0.f;
    __syncthreads();

    if (t < 3 * Kn) {
        const float4* wrow = (const float4*)(W + (size_t)t * CELLn);
        const float4* xr   = (const float4*)s_x;
        float a0 = 0.f, a1 = 0.f, a2 = 0.f, a3 = 0.f;
        #pragma unroll 8
        for (int i = 0; i < CELLn / 4; ++i) {
            float4 wv = wrow[i];
            float4 xv = xr[i];
            a0 = fmaf(wv.x, xv.x, a0);
            a1 = fmaf(wv.y, xv.y, a1);
            a2 = fmaf(wv.z, xv.z, a2);
            a3 = fmaf(wv.w, xv.w, a3);
        }
        float val = expf((a0 + a1) + (a2 + a3) + bias[t]);
        if (t >= 2 * Kn) {  // pre_kappa -> kappa
            int k = t - 2 * Kn;
            float kap = kappa_old[(size_t)b * Kn + k] + val;
            s_abk[t] = kap;
            out_kappa[(size_t)b * Kn + k] = kap;
        } else {
            s_abk[t] = val;  // alpha or beta
        }
    }
    __syncthreads();

    const float scale = (float)Ln / text_lens[b];
    for (int l = t; l <= Ln; l += NTA) {
        const float fl = (float)l;
        float acc = 0.f;
        #pragma unroll
        for (int k = 0; k < Kn; ++k) {
            float d = s_abk[2 * Kn + k] - fl;
            acc = fmaf(s_abk[k], expf(-s_abk[Kn + k] * d * d), acc);
        }
        out_phi[(size_t)b * (Ln + 1) + l] = acc * scale;
    }
}

// Kernel B: w[b,v] += sum_{l in chunk} phi[b,l] * onehots[b,l,v]
// Pure 671 MB HBM stream. grid = (CH, B); each block streams 80 KB with a
// fully unrolled 16-load body (16 outstanding float4 loads per thread).
__global__ __launch_bounds__(NTB) void window_w(
    const float* __restrict__ onehots,  // [B, L, V]
    const float* __restrict__ phi,      // [B, L+1]
    float* __restrict__ out_w)          // [B, V]
{
    const int c = blockIdx.x;
    const int b = blockIdx.y;
    const int t = threadIdx.x;

    __shared__ float s_phi[CHL];        // 1 KB
    __shared__ float s_red[16][Vn];     // 5 KB

    if (t < CHL) s_phi[t] = phi[(size_t)b * (Ln + 1) + c * CHL + t];
    __syncthreads();

    const int j  = t % 20;  // column quad: v = 4j..4j+3
    const int r0 = t / 20;  // row phase 0..15
    const float4* oh = (const float4*)(onehots + (size_t)b * Ln * Vn)
                       + (size_t)(c * CHL) * 20;
    float4 acc = make_float4(0.f, 0.f, 0.f, 0.f);
    #pragma unroll
    for (int i = 0; i < 16; ++i) {
        const int l = r0 + 16 * i;
        float4 v = oh[l * 20 + j];   // wave = 64 consecutive float4s, 1 KB coalesced
        float ph = s_phi[l];
        acc.x = fmaf(ph, v.x, acc.x);
        acc.y = fmaf(ph, v.y, acc.y);
        acc.z = fmaf(ph, v.z, acc.z);
        acc.w = fmaf(ph, v.w, acc.w);
    }
    *((float4*)&s_red[r0][j * 4]) = acc;
    __syncthreads();

    if (t < Vn) {
        float s = 0.f;
        #pragma unroll
        for (int r = 0; r < 16; ++r) s += s_red[r][t];
        atomicAdd(&out_w[(size_t)b * Vn + t], s);
    }
}

extern "C" void kernel_launch(void* const* d_in, const int* in_sizes, int n_in,
                              void* d_out, int out_size, void* d_ws, size_t ws_size,
                              hipStream_t stream) {
    const float* x         = (const float*)d_in[0];
    const float* kappa_old = (const float*)d_in[1];
    const float* onehots   = (const float*)d_in[2];
    const float* text_lens = (const float*)d_in[3];
    const float* W         = (const float*)d_in[4];
    const float* bias      = (const float*)d_in[5];

    float* out       = (float*)d_out;
    float* out_w     = out;                                  // [B, V]
    float* out_kappa = out + (size_t)Bn * Vn;                // [B, K]
    float* out_phi   = out_kappa + (size_t)Bn * Kn;          // [B, L+1]

    window_params_phi<<<Bn, NTA, 0, stream>>>(x, kappa_old, text_lens, W, bias,
                                              out_w, out_kappa, out_phi);
    window_w<<<dim3(CH, Bn), NTB, 0, stream>>>(onehots, out_phi, out_w);
}

// Round 3
// 893.258 us; speedup vs baseline: 1.0921x; 1.0320x over previous
//
#include <hip/hip_runtime.h>
#include <math.h>

// Problem constants (match reference)
namespace {
constexpr int Bn    = 2048;
constexpr int CELLn = 512;
constexpr int Kn    = 30;   // alpha/beta/kappa each [B,30]
constexpr int Ln    = 1024; // padded text len
constexpr int Vn    = 80;   // vocab
constexpr int NTA   = 256;  // kernel A block
constexpr int NTB   = 640;  // kernel B block: 32 row-phases x 20 col-quads (10 waves)
constexpr int RP    = NTB / 20;  // 32 row phases
}

typedef float f4v __attribute__((ext_vector_type(4)));

// Kernel A: params = exp(x@W.T + b), kappa = kappa_old + pre_kappa, phi -> HBM.
__global__ __launch_bounds__(NTA) void window_params_phi(
    const float* __restrict__ x,          // [B, CELL]
    const float* __restrict__ kappa_old,  // [B, K]
    const float* __restrict__ text_lens,  // [B, 1]
    const float* __restrict__ W,          // [3K, CELL]
    const float* __restrict__ bias,       // [3K]
    float* __restrict__ out_kappa,        // [B, K]
    float* __restrict__ out_phi)          // [B, L+1]
{
    const int b = blockIdx.x;
    const int t = threadIdx.x;

    __shared__ float s_x[CELLn];    // 2 KB
    __shared__ float s_abk[3 * Kn]; // alpha[0:30], beta[30:60], kappa[60:90]

    if (t < 128) ((float4*)s_x)[t] = ((const float4*)(x + (size_t)b * CELLn))[t];
    __syncthreads();

    if (t < 3 * Kn) {
        const float4* wrow = (const float4*)(W + (size_t)t * CELLn);
        const float4* xr   = (const float4*)s_x;
        float a0 = 0.f, a1 = 0.f, a2 = 0.f, a3 = 0.f;
        #pragma unroll 8
        for (int i = 0; i < CELLn / 4; ++i) {
            float4 wv = wrow[i];
            float4 xv = xr[i];
            a0 = fmaf(wv.x, xv.x, a0);
            a1 = fmaf(wv.y, xv.y, a1);
            a2 = fmaf(wv.z, xv.z, a2);
            a3 = fmaf(wv.w, xv.w, a3);
        }
        float val = expf((a0 + a1) + (a2 + a3) + bias[t]);
        if (t >= 2 * Kn) {  // pre_kappa -> kappa
            int k = t - 2 * Kn;
            float kap = kappa_old[(size_t)b * Kn + k] + val;
            s_abk[t] = kap;
            out_kappa[(size_t)b * Kn + k] = kap;
        } else {
            s_abk[t] = val;  // alpha or beta
        }
    }
    __syncthreads();

    const float scale = (float)Ln / text_lens[b];
    for (int l = t; l <= Ln; l += NTA) {
        const float fl = (float)l;
        float acc = 0.f;
        #pragma unroll
        for (int k = 0; k < Kn; ++k) {
            float d = s_abk[2 * Kn + k] - fl;
            acc = fmaf(s_abk[k], expf(-s_abk[Kn + k] * d * d), acc);
        }
        out_phi[(size_t)b * (Ln + 1) + l] = acc * scale;
    }
}

// Kernel B: w[b,v] = sum_l phi[b,l] * onehots[b,l,v].
// One block per batch row: streams 320 KB contiguously (wave = 64 consecutive
// float4s = 1 KB per load instr), nontemporal (zero reuse -> spare L2).
// Thread stride is 640 float4s = 32*20, so j = t%20 (the v-quad) is invariant
// per thread and the accumulator stays in 4 registers.
__global__ __launch_bounds__(NTB) void window_w(
    const float* __restrict__ onehots,  // [B, L, V]
    const float* __restrict__ phi,      // [B, L+1]
    float* __restrict__ out_w)          // [B, V]
{
    const int b = blockIdx.x;
    const int t = threadIdx.x;

    __shared__ float s_phi[Ln];         // 4 KB
    __shared__ float s_red[RP][Vn];     // 10 KB

    if (t < Ln / 4) ((float4*)s_phi)[t] = ((const float4*)(phi + (size_t)b * (Ln + 1)))[t];
    __syncthreads();

    const int j  = t % 20;  // column quad: v = 4j..4j+3 (fixed per thread)
    const int r0 = t / 20;  // row phase 0..31
    const f4v* oh = (const f4v*)(onehots + (size_t)b * Ln * Vn);

    f4v acc = {0.f, 0.f, 0.f, 0.f};
    #pragma unroll 8
    for (int i = 0; i < Ln / RP; ++i) {     // 32 iterations, 8 loads in flight
        const int l = r0 + RP * i;
        f4v v = __builtin_nontemporal_load(&oh[l * 20 + j]);
        acc += s_phi[l] * v;
    }
    *((f4v*)&s_red[r0][j * 4]) = acc;
    __syncthreads();

    if (t < Vn) {
        float s = 0.f;
        #pragma unroll
        for (int r = 0; r < RP; ++r) s += s_red[r][t];
        out_w[(size_t)b * Vn + t] = s;
    }
}

extern "C" void kernel_launch(void* const* d_in, const int* in_sizes, int n_in,
                              void* d_out, int out_size, void* d_ws, size_t ws_size,
                              hipStream_t stream) {
    const float* x         = (const float*)d_in[0];
    const float* kappa_old = (const float*)d_in[1];
    const float* onehots   = (const float*)d_in[2];
    const float* text_lens = (const float*)d_in[3];
    const float* W         = (const float*)d_in[4];
    const float* bias      = (const float*)d_in[5];

    float* out       = (float*)d_out;
    float* out_w     = out;                                  // [B, V]
    float* out_kappa = out + (size_t)Bn * Vn;                // [B, K]
    float* out_phi   = out_kappa + (size_t)Bn * Kn;          // [B, L+1]

    window_params_phi<<<Bn, NTA, 0, stream>>>(x, kappa_old, text_lens, W, bias,
                                              out_kappa, out_phi);
    window_w<<<Bn, NTB, 0, stream>>>(onehots, out_phi, out_w);
}

// Round 4
// 806.340 us; speedup vs baseline: 1.2098x; 1.1078x over previous
//
#include <hip/hip_runtime.h>
#include <math.h>

// Problem constants (match reference)
namespace {
constexpr int Bn    = 2048;
constexpr int CELLn = 512;
constexpr int Kn    = 30;   // alpha/beta/kappa each [B,30]
constexpr int Ln    = 1024; // padded text len
constexpr int Vn    = 80;   // vocab
constexpr int NT    = 320;  // 5 waves: 16 row-phases x 20 col-quads for the stream
constexpr int RP    = 16;   // row phases in the stream
}

typedef float f4v __attribute__((ext_vector_type(4)));

// Fully fused: params GEMV -> phi -> per-row effective length -> sparse w stream.
//
// Key algorithmic fact: phi[b,l] = sum_k alpha_k exp(-beta_k (kappa_k - l)^2)
// underflows to EXACTLY 0.0f for l beyond ~kappa_max + sqrt(103/beta_min)
// (typically l ~ 30..90 of 1024). Terms with phi[b,l]==0.0f contribute
// exactly nothing to w — bit-identical to the dense sum over our own phi —
// so we stream only onehot rows l < n_eff(b), cutting the dominant HBM read
// from 671 MB to ~tens of MB. Worst case (wide window) degrades gracefully
// to the full stream.
__global__ __launch_bounds__(NT) void window_fused(
    const float* __restrict__ x,          // [B, CELL]
    const float* __restrict__ kappa_old,  // [B, K]
    const float* __restrict__ onehots,    // [B, L, V]
    const float* __restrict__ text_lens,  // [B, 1]
    const float* __restrict__ W,          // [3K, CELL]
    const float* __restrict__ bias,       // [3K]
    float* __restrict__ out_w,            // [B, V]
    float* __restrict__ out_kappa,        // [B, K]
    float* __restrict__ out_phi)          // [B, L+1]
{
    const int b = blockIdx.x;
    const int t = threadIdx.x;

    __shared__ float s_x[CELLn];     // 2 KB
    __shared__ float s_abk[3 * Kn];  // alpha[0:30], beta[30:60], kappa[60:90]
    __shared__ float s_phi[Ln];      // 4 KB
    __shared__ float s_red[RP][Vn];  // 5 KB
    __shared__ int   s_nmax;

    // ---- stage x row ----
    if (t < 128) ((float4*)s_x)[t] = ((const float4*)(x + (size_t)b * CELLn))[t];
    if (t == 128) s_nmax = 0;
    __syncthreads();

    // ---- params = exp(x@W.T + b); kappa = kappa_old + pre_kappa ----
    if (t < 3 * Kn) {
        const float4* wrow = (const float4*)(W + (size_t)t * CELLn);
        const float4* xr   = (const float4*)s_x;
        float a0 = 0.f, a1 = 0.f, a2 = 0.f, a3 = 0.f;
        #pragma unroll 8
        for (int i = 0; i < CELLn / 4; ++i) {
            float4 wv = wrow[i];
            float4 xv = xr[i];
            a0 = fmaf(wv.x, xv.x, a0);
            a1 = fmaf(wv.y, xv.y, a1);
            a2 = fmaf(wv.z, xv.z, a2);
            a3 = fmaf(wv.w, xv.w, a3);
        }
        float val = expf((a0 + a1) + (a2 + a3) + bias[t]);
        if (t >= 2 * Kn) {  // pre_kappa -> kappa
            int k = t - 2 * Kn;
            float kap = kappa_old[(size_t)b * Kn + k] + val;
            s_abk[t] = kap;
            out_kappa[(size_t)b * Kn + k] = kap;
        } else {
            s_abk[t] = val;  // alpha or beta
        }
    }
    __syncthreads();

    // ---- phi + effective window length ----
    const float scale = (float)Ln / text_lens[b];
    for (int l = t; l <= Ln; l += NT) {
        const float fl = (float)l;
        float acc = 0.f;
        #pragma unroll
        for (int k = 0; k < Kn; ++k) {
            float d = s_abk[2 * Kn + k] - fl;
            acc = fmaf(s_abk[k], expf(-s_abk[Kn + k] * d * d), acc);
        }
        float ph = acc * scale;
        out_phi[(size_t)b * (Ln + 1) + l] = ph;
        if (l < Ln) {
            s_phi[l] = ph;
            if (ph != 0.f) atomicMax(&s_nmax, l + 1);  // shared-scope, ~n_eff ops
        }
    }
    __syncthreads();
    const int n_eff = s_nmax;  // rows beyond this have phi == 0.0f exactly

    // ---- w[v] = sum_{l<n_eff} phi[l] * onehots[b,l,v] ----
    const int j  = t % 20;  // column quad: v = 4j..4j+3 (fixed per thread)
    const int r0 = t / 20;  // row phase 0..15
    const f4v* oh = (const f4v*)(onehots + (size_t)b * Ln * Vn);

    f4v acc = {0.f, 0.f, 0.f, 0.f};
    #pragma unroll 2
    for (int l = r0; l < n_eff; l += RP) {
        f4v v = oh[l * 20 + j];   // wave = 64 consecutive float4s, coalesced
        acc += s_phi[l] * v;
    }
    *((f4v*)&s_red[r0][j * 4]) = acc;
    __syncthreads();

    if (t < Vn) {
        float s = 0.f;
        #pragma unroll
        for (int r = 0; r < RP; ++r) s += s_red[r][t];
        out_w[(size_t)b * Vn + t] = s;
    }
}

extern "C" void kernel_launch(void* const* d_in, const int* in_sizes, int n_in,
                              void* d_out, int out_size, void* d_ws, size_t ws_size,
                              hipStream_t stream) {
    const float* x         = (const float*)d_in[0];
    const float* kappa_old = (const float*)d_in[1];
    const float* onehots   = (const float*)d_in[2];
    const float* text_lens = (const float*)d_in[3];
    const float* W         = (const float*)d_in[4];
    const float* bias      = (const float*)d_in[5];

    float* out       = (float*)d_out;
    float* out_w     = out;                                  // [B, V]
    float* out_kappa = out + (size_t)Bn * Vn;                // [B, K]
    float* out_phi   = out_kappa + (size_t)Bn * Kn;          // [B, L+1]

    window_fused<<<Bn, NT, 0, stream>>>(x, kappa_old, onehots, text_lens, W, bias,
                                        out_w, out_kappa, out_phi);
}